// Round 3
// baseline (4154.135 us; speedup 1.0000x reference)
//
#include <hip/hip_runtime.h>
#include <hip/hip_fp16.h>

// Bidirectional GRU (B=64,S=1024,E=H=256) + FC/ReLU head — chunked pipeline.
// k_gx: gx = x@W_ih^T (+b) both dirs, f16 MFMA, f16 consumer-ordered out.
// k_rec: persistent 8 WGs (2 dir x 4 bslice), 512 thr, W_hh f16 frags in VGPRs
//        (launch_bounds(512,2) -> ~512-reg budget, no AGPR shuffling),
//        ping-pong hs + ONE lgkm-only barrier/step, gx prefetched 1 step ahead.
// k_fc: relu(concat @ W_fc^T + b) in place over the f16 h written into d_out.

typedef _Float16 f16x8 __attribute__((ext_vector_type(8)));
typedef _Float16 f16x4 __attribute__((ext_vector_type(4)));
typedef float    f32x4 __attribute__((ext_vector_type(4)));

#define MFMA(a,b,c) __builtin_amdgcn_mfma_f32_16x16x32_f16((a),(b),(c),0,0,0)
// swizzled byte addr for [rows][256 f16] (512B rows) and [rows][512 f16] (1024B rows)
#define SWZ(r,c)  ((((r)*512)  + (c)) ^ (((r)&7)<<4))
#define SWZ2(r,c) ((((r)*1024) + (c)) ^ (((r)&7)<<4))

__device__ inline f16x8 pack8(float4 a, float4 b){
  f16x8 h;
  h[0]=(_Float16)a.x; h[1]=(_Float16)a.y; h[2]=(_Float16)a.z; h[3]=(_Float16)a.w;
  h[4]=(_Float16)b.x; h[5]=(_Float16)b.y; h[6]=(_Float16)b.z; h[7]=(_Float16)b.w;
  return h;
}
__device__ inline float fsigm(float x){
  return __builtin_amdgcn_rcpf(1.f + __expf(-x));
}
__device__ inline float ftanh(float x){
  float e = __expf(2.f*x);                   // +inf -> 1, 0 -> -1
  return 1.f - 2.f*__builtin_amdgcn_rcpf(e + 1.f);
}

// ---------------- gx chunk: gx = x @ W_ih^T + b_ih (+ b_hh for r,z) ----------------
__global__ __launch_bounds__(256) void k_gx(
    const float* __restrict__ X,
    const float* __restrict__ Wf, const float* __restrict__ bihf, const float* __restrict__ bhhf,
    const float* __restrict__ Wb, const float* __restrict__ bihb, const float* __restrict__ bhhb,
    _Float16* __restrict__ gxc, int CT, int sbase)
{
  const int tc = blockIdx.x, dir = blockIdx.y;
  const int p = sbase + tc;
  const int t = dir ? (1023 - p) : p;
  const float* __restrict__ Wp = dir ? Wb : Wf;
  const float* __restrict__ bi = dir ? bihb : bihf;
  const float* __restrict__ bh = dir ? bhhb : bhhf;
  __shared__ _Float16 As[64*256];            // 32KB
  __shared__ _Float16 Bs[64*256];            // 32KB
  const int tid = threadIdx.x;
  #pragma unroll
  for (int i = 0; i < 8; ++i) {              // stage A: rows = batch b, fixed t
    int c = tid + i*256, r = c >> 5, cc = c & 31;
    const float4* s4 = (const float4*)(X + ((size_t)r*1024 + t)*256 + cc*8);
    *(f16x8*)((char*)As + SWZ(r, cc*16)) = pack8(s4[0], s4[1]);
  }
  const int w = tid >> 6, l = tid & 63, lr = l & 15, g = l >> 4;
  const size_t obase = (((size_t)dir*CT + tc)*4 + w) * (size_t)(512*24);
  #pragma unroll 1
  for (int nt = 0; nt < 12; ++nt) {
    __syncthreads();
    #pragma unroll
    for (int i = 0; i < 8; ++i) {            // stage B: W rows nt*64..+64
      int c = tid + i*256, r = c >> 5, cc = c & 31;
      const float4* s4 = (const float4*)(Wp + (size_t)(nt*64 + r)*256 + cc*8);
      *(f16x8*)((char*)Bs + SWZ(r, cc*16)) = pack8(s4[0], s4[1]);
    }
    __syncthreads();
    f32x4 acc[4];
    #pragma unroll
    for (int ct = 0; ct < 4; ++ct) acc[ct] = (f32x4){0.f,0.f,0.f,0.f};
    #pragma unroll
    for (int kk = 0; kk < 8; ++kk) {
      f16x8 af = *(const f16x8*)((const char*)As + SWZ(w*16 + lr, kk*64 + g*16));
      #pragma unroll
      for (int ct = 0; ct < 4; ++ct) {
        f16x8 bfr = *(const f16x8*)((const char*)Bs + SWZ(ct*16 + lr, kk*64 + g*16));
        acc[ct] = MFMA(af, bfr, acc[ct]);
      }
    }
    #pragma unroll
    for (int ct = 0; ct < 4; ++ct) {         // consumer-ordered, q-contiguous: 8B stores
      const int col = nt*64 + ct*16 + lr;
      const float bv = bi[col] + (col < 512 ? bh[col] : 0.f);
      const int jj = col & 255;
      const int tid2 = (jj>>5)*64 + g*16 + lr;
      const int idx0 = ((col>>8)*2 + ((jj>>4)&1))*4;   // gate*8 + jt*4
      f16x4 v;
      #pragma unroll
      for (int q = 0; q < 4; ++q) v[q] = (_Float16)(acc[ct][q] + bv);
      *(f16x4*)(gxc + obase + (size_t)tid2*24 + idx0) = v;
    }
  }
}

// ---------------- GRU recurrence, one chunk of CT steps ----------------
// One step: MFMA(read hs[RBUF]) -> prefetch gx(s+1) -> gates (consume gx(s),
// write hs[RBUF^1], store out16) -> lgkmcnt(0)+s_barrier. Ping-pong buffers
// make read-set and write-set disjoint -> single barrier per step; global
// loads/stores are never drained at the barrier.
__global__ __launch_bounds__(512, 2) void k_rec(
    const float* __restrict__ Whh_f, const float* __restrict__ bhh_f,
    const float* __restrict__ Whh_b, const float* __restrict__ bhh_b,
    const _Float16* __restrict__ gxc, float* __restrict__ wsh,
    _Float16* __restrict__ out16, float* __restrict__ hidden,
    int CT, int sbase)
{
  const int dir = blockIdx.x & 1;
  const int bsl = blockIdx.x >> 1;
  const int bbase = bsl * 16;
  const float* __restrict__ Whh = dir ? Whh_b : Whh_f;
  const float* __restrict__ bhh = dir ? bhh_b : bhh_f;
  const int tid = threadIdx.x, w = tid >> 6, l = tid & 63;
  const int lr = l & 15, g = l >> 4;
  const int j0 = w * 32;
  f16x8 wf[6][8];                            // B-frag: W[col][k=kk*32+g*8+i] — VGPR-resident
  #pragma unroll
  for (int ct = 0; ct < 6; ++ct) {
    const int colg = (ct>>1)*256 + j0 + (ct&1)*16 + lr;
    #pragma unroll
    for (int kk = 0; kk < 8; ++kk) {
      const float4* s4 = (const float4*)(Whh + (size_t)colg*256 + kk*32 + g*8);
      wf[ct][kk] = pack8(s4[0], s4[1]);
    }
  }
  const float bn0 = bhh[512 + j0 + lr];      // n-gate bhh (inside r*(.))
  const float bn1 = bhh[512 + j0 + 16 + lr];
  __shared__ _Float16 hs[2][16*256];         // ping-pong h tiles, swizzled
  float hold[2][4];
  if (sbase == 0) {
    *(int4*)((char*)hs[0] + tid*16) = make_int4(0,0,0,0);
    #pragma unroll
    for (int jt = 0; jt < 2; ++jt)
      #pragma unroll
      for (int q = 0; q < 4; ++q) hold[jt][q] = 0.f;
  } else {
    const int r = tid >> 5, cc = tid & 31;
    const float4* s4 = (const float4*)(wsh + ((size_t)(dir*64 + bbase + r))*256 + cc*8);
    *(f16x8*)((char*)hs[0] + SWZ(r, cc*16)) = pack8(s4[0], s4[1]);
    #pragma unroll
    for (int jt = 0; jt < 2; ++jt)
      #pragma unroll
      for (int q = 0; q < 4; ++q)
        hold[jt][q] = wsh[((size_t)(dir*64 + bbase + g*4 + q))*256 + j0 + jt*16 + lr];
  }
  __syncthreads();

  // hoisted moving pointers
  const int t0 = dir ? (1023 - sbase) : sbase;
  char* optr = (char*)out16 + ((size_t)t0*64 + bbase + g*4)*1024
             + (size_t)(dir*256 + j0 + lr)*2;
  const ptrdiff_t ostep = dir ? -(ptrdiff_t)65536 : (ptrdiff_t)65536;
  const _Float16* gp = gxc + (((size_t)dir*CT)*4 + bsl)*(size_t)(512*24) + (size_t)tid*24;
  const ptrdiff_t gstep = 4*512*24;
  // prologue prefetch (sc=0)
  f16x8 ga0 = *(const f16x8*)(gp);
  f16x8 ga1 = *(const f16x8*)(gp + 8);
  f16x8 ga2 = *(const f16x8*)(gp + 16);
  gp += gstep;
  f16x8 gb0, gb1, gb2;

  // NOTE: last prefetch overruns by one step; lands in [gxc_end, gxc_end+96KB)
  // which is inside the 128KB wsh slab -> in-bounds garbage, never consumed.
#define REC_STEP(RBUF, GC0,GC1,GC2, GN0,GN1,GN2)                                   \
  {                                                                                \
    f32x4 acc[6];                                                                  \
    acc[0] = acc[1] = acc[2] = acc[3] = (f32x4){0.f,0.f,0.f,0.f};                  \
    acc[4] = (f32x4){bn0,bn0,bn0,bn0};                                             \
    acc[5] = (f32x4){bn1,bn1,bn1,bn1};                                             \
    _Pragma("unroll")                                                              \
    for (int kk = 0; kk < 8; ++kk) {                                               \
      f16x8 af = *(const f16x8*)((const char*)hs + (RBUF)*8192 + SWZ(lr, kk*64 + g*16)); \
      _Pragma("unroll")                                                            \
      for (int ct = 0; ct < 6; ++ct) acc[ct] = MFMA(af, wf[ct][kk], acc[ct]);      \
    }                                                                              \
    GN0 = *(const f16x8*)(gp);                                                     \
    GN1 = *(const f16x8*)(gp + 8);                                                 \
    GN2 = *(const f16x8*)(gp + 16);                                                \
    gp += gstep;                                                                   \
    _Pragma("unroll")                                                              \
    for (int jt = 0; jt < 2; ++jt) {                                               \
      _Pragma("unroll")                                                            \
      for (int q = 0; q < 4; ++q) {                                                \
        const float r = fsigm((float)GC0[jt*4+q] + acc[jt][q]);                    \
        const float z = fsigm((float)GC1[jt*4+q] + acc[2+jt][q]);                  \
        const float n = ftanh((float)GC2[jt*4+q] + r*acc[4+jt][q]);                \
        const float h = n + z*(hold[jt][q] - n);                                   \
        hold[jt][q] = h;                                                           \
        *(_Float16*)((char*)hs + ((RBUF)^1)*8192 + SWZ(g*4+q, (j0+jt*16+lr)*2)) = (_Float16)h; \
        *(_Float16*)(optr + q*1024 + jt*32) = (_Float16)h;                         \
      }                                                                            \
    }                                                                              \
    optr += ostep;                                                                 \
    __builtin_amdgcn_sched_barrier(0);                                             \
    asm volatile("s_waitcnt lgkmcnt(0)" ::: "memory");                             \
    __builtin_amdgcn_sched_barrier(0);                                             \
    __builtin_amdgcn_s_barrier();                                                  \
  }

  #pragma unroll 1
  for (int sc = 0; sc < CT; sc += 2) {
    REC_STEP(0, ga0,ga1,ga2, gb0,gb1,gb2)
    REC_STEP(1, gb0,gb1,gb2, ga0,ga1,ga2)
  }
#undef REC_STEP

  if (sbase + CT == 1024) {                  // final h -> hidden output
    #pragma unroll
    for (int jt = 0; jt < 2; ++jt)
      #pragma unroll
      for (int q = 0; q < 4; ++q)
        hidden[((size_t)(dir*64 + bbase + g*4 + q))*256 + j0 + jt*16 + lr] = hold[jt][q];
  } else {                                   // persist h for next chunk
    #pragma unroll
    for (int jt = 0; jt < 2; ++jt)
      #pragma unroll
      for (int q = 0; q < 4; ++q)
        wsh[((size_t)(dir*64 + bbase + g*4 + q))*256 + j0 + jt*16 + lr] = hold[jt][q];
  }
}

// ---------------- FC in place: relu(concat_f16 @ W_fc^T + b) -> f32 ----------------
__global__ __launch_bounds__(256) void k_fc(
    const _Float16* __restrict__ h16, const float* __restrict__ Wfc,
    const float* __restrict__ bfc, float* __restrict__ out)
{
  const int mt = blockIdx.x;
  __shared__ _Float16 As[64*512];            // 64KB
  const int tid = threadIdx.x, w = tid >> 6, l = tid & 63;
  const int lr = l & 15, g = l >> 4;
  #pragma unroll
  for (int i = 0; i < 16; ++i) {
    int c = tid + i*256, r = c >> 6, cc = c & 63;
    *(int4*)((char*)As + SWZ2(r, cc*16)) =
        *(const int4*)((const char*)h16 + ((size_t)mt*64 + r)*1024 + cc*16);
  }
  __syncthreads();                           // all h16 reads drained before any store
  #pragma unroll 1
  for (int nt = 0; nt < 4; ++nt) {
    f32x4 acc[4];
    #pragma unroll
    for (int ct = 0; ct < 4; ++ct) acc[ct] = (f32x4){0.f,0.f,0.f,0.f};
    #pragma unroll 2
    for (int kk = 0; kk < 16; ++kk) {
      f16x8 af = *(const f16x8*)((const char*)As + SWZ2(w*16 + lr, kk*64 + g*16));
      #pragma unroll
      for (int ct = 0; ct < 4; ++ct) {
        const float4* s4 = (const float4*)(Wfc + (size_t)(nt*64 + ct*16 + lr)*512 + kk*32 + g*8);
        acc[ct] = MFMA(af, pack8(s4[0], s4[1]), acc[ct]);
      }
    }
    #pragma unroll
    for (int ct = 0; ct < 4; ++ct) {
      const int col = nt*64 + ct*16 + lr;
      const float bv = bfc[col];
      #pragma unroll
      for (int q = 0; q < 4; ++q) {
        const int row = w*16 + g*4 + q;
        out[((size_t)mt*64 + row)*256 + col] = fmaxf(acc[ct][q] + bv, 0.f);
      }
    }
  }
}

extern "C" void kernel_launch(void* const* d_in, const int* in_sizes, int n_in,
                              void* d_out, int out_size, void* d_ws, size_t ws_size,
                              hipStream_t stream) {
  const float* X      = (const float*)d_in[0];
  const float* W_ih_f = (const float*)d_in[1];
  const float* W_hh_f = (const float*)d_in[2];
  const float* b_ih_f = (const float*)d_in[3];
  const float* b_hh_f = (const float*)d_in[4];
  const float* W_ih_b = (const float*)d_in[5];
  const float* W_hh_b = (const float*)d_in[6];
  const float* b_ih_b = (const float*)d_in[7];
  const float* b_hh_b = (const float*)d_in[8];
  const float* W_fc   = (const float*)d_in[9];
  const float* b_fc   = (const float*)d_in[10];

  // Pick chunk length from ws_size: need CT*196608 + 131072 bytes.
  int CT = 1024;
  while (CT > 8 && ((size_t)CT*196608 + 131072) > ws_size) CT >>= 1;
  _Float16* gxc = (_Float16*)d_ws;                     // [2][CT][4][512][24] f16
  float*    wsh = (float*)((char*)d_ws + (size_t)CT*196608);  // [2][64][256] f32

  _Float16* h16   = (_Float16*)d_out;                  // [1024][64][512] f16 (in-place)
  float*    out   = (float*)d_out;                     // [1024][64][256] f32
  float*    hidden= (float*)d_out + (size_t)1024*64*256;

  const int NC = 1024 / CT;
  for (int c = 0; c < NC; ++c) {
    k_gx<<<dim3(CT, 2), dim3(256), 0, stream>>>(X, W_ih_f, b_ih_f, b_hh_f,
                                                W_ih_b, b_ih_b, b_hh_b, gxc, CT, c*CT);
    k_rec<<<dim3(8), dim3(512), 0, stream>>>(W_hh_f, b_hh_f, W_hh_b, b_hh_b,
                                             gxc, wsh, h16, hidden, CT, c*CT);
  }
  k_fc<<<dim3(1024), dim3(256), 0, stream>>>(h16, W_fc, b_fc, out);
}

// Round 4
// 3016.012 us; speedup vs baseline: 1.3774x; 1.3774x over previous
//
#include <hip/hip_runtime.h>
#include <hip/hip_fp16.h>

// Bidirectional GRU (B=64,S=1024,E=H=256) + FC/ReLU head — chunked pipeline.
// k_gx: gx = x@W_ih^T (+b) both dirs, f16 MFMA, f16 consumer-ordered out.
// k_rec: persistent 8 WGs (2 dir x 4 bslice), 512 thr. W_hh f16 frags reg-resident.
//        h stored in LDS in MFMA-A-FRAGMENT ORDER (haf[kk][lane][i]) -> af reads are
//        ds_read_b128 at lane*16 + kk*1024: linear, conflict-free, zero addr math.
//        Ping-pong haf tiles, ONE __syncthreads per step (compiler-scheduled),
//        gx loaded at step top, out16 stores deferred one step (full step to drain).
// k_fc: relu(concat @ W_fc^T + b) in place over the f16 h written into d_out.

typedef _Float16 f16x8 __attribute__((ext_vector_type(8)));
typedef _Float16 f16x4 __attribute__((ext_vector_type(4)));
typedef float    f32x4 __attribute__((ext_vector_type(4)));

#define MFMA(a,b,c) __builtin_amdgcn_mfma_f32_16x16x32_f16((a),(b),(c),0,0,0)
// swizzled byte addr (k_gx/k_fc staging tiles only)
#define SWZ(r,c)  ((((r)*512)  + (c)) ^ (((r)&7)<<4))
#define SWZ2(r,c) ((((r)*1024) + (c)) ^ (((r)&7)<<4))

__device__ inline f16x8 pack8(float4 a, float4 b){
  f16x8 h;
  h[0]=(_Float16)a.x; h[1]=(_Float16)a.y; h[2]=(_Float16)a.z; h[3]=(_Float16)a.w;
  h[4]=(_Float16)b.x; h[5]=(_Float16)b.y; h[6]=(_Float16)b.z; h[7]=(_Float16)b.w;
  return h;
}
__device__ inline float fsigm(float x){
  return __builtin_amdgcn_rcpf(1.f + __expf(-x));
}
__device__ inline float ftanh(float x){
  float e = __expf(2.f*x);                   // +inf -> 1, 0 -> -1
  return 1.f - 2.f*__builtin_amdgcn_rcpf(e + 1.f);
}

// ---------------- gx chunk: gx = x @ W_ih^T + b_ih (+ b_hh for r,z) ----------------
__global__ __launch_bounds__(256) void k_gx(
    const float* __restrict__ X,
    const float* __restrict__ Wf, const float* __restrict__ bihf, const float* __restrict__ bhhf,
    const float* __restrict__ Wb, const float* __restrict__ bihb, const float* __restrict__ bhhb,
    _Float16* __restrict__ gxc, int CT, int sbase)
{
  const int tc = blockIdx.x, dir = blockIdx.y;
  const int p = sbase + tc;
  const int t = dir ? (1023 - p) : p;
  const float* __restrict__ Wp = dir ? Wb : Wf;
  const float* __restrict__ bi = dir ? bihb : bihf;
  const float* __restrict__ bh = dir ? bhhb : bhhf;
  __shared__ _Float16 As[64*256];            // 32KB
  __shared__ _Float16 Bs[64*256];            // 32KB
  const int tid = threadIdx.x;
  #pragma unroll
  for (int i = 0; i < 8; ++i) {              // stage A: rows = batch b, fixed t
    int c = tid + i*256, r = c >> 5, cc = c & 31;
    const float4* s4 = (const float4*)(X + ((size_t)r*1024 + t)*256 + cc*8);
    *(f16x8*)((char*)As + SWZ(r, cc*16)) = pack8(s4[0], s4[1]);
  }
  const int w = tid >> 6, l = tid & 63, lr = l & 15, g = l >> 4;
  const size_t obase = (((size_t)dir*CT + tc)*4 + w) * (size_t)(512*24);
  #pragma unroll 1
  for (int nt = 0; nt < 12; ++nt) {
    __syncthreads();
    #pragma unroll
    for (int i = 0; i < 8; ++i) {            // stage B: W rows nt*64..+64
      int c = tid + i*256, r = c >> 5, cc = c & 31;
      const float4* s4 = (const float4*)(Wp + (size_t)(nt*64 + r)*256 + cc*8);
      *(f16x8*)((char*)Bs + SWZ(r, cc*16)) = pack8(s4[0], s4[1]);
    }
    __syncthreads();
    f32x4 acc[4];
    #pragma unroll
    for (int ct = 0; ct < 4; ++ct) acc[ct] = (f32x4){0.f,0.f,0.f,0.f};
    #pragma unroll
    for (int kk = 0; kk < 8; ++kk) {
      f16x8 af = *(const f16x8*)((const char*)As + SWZ(w*16 + lr, kk*64 + g*16));
      #pragma unroll
      for (int ct = 0; ct < 4; ++ct) {
        f16x8 bfr = *(const f16x8*)((const char*)Bs + SWZ(ct*16 + lr, kk*64 + g*16));
        acc[ct] = MFMA(af, bfr, acc[ct]);
      }
    }
    #pragma unroll
    for (int ct = 0; ct < 4; ++ct) {         // consumer-ordered, q-contiguous: 8B stores
      const int col = nt*64 + ct*16 + lr;
      const float bv = bi[col] + (col < 512 ? bh[col] : 0.f);
      const int jj = col & 255;
      const int tid2 = (jj>>5)*64 + g*16 + lr;
      const int idx0 = ((col>>8)*2 + ((jj>>4)&1))*4;   // gate*8 + jt*4
      f16x4 v;
      #pragma unroll
      for (int q = 0; q < 4; ++q) v[q] = (_Float16)(acc[ct][q] + bv);
      *(f16x4*)(gxc + obase + (size_t)tid2*24 + idx0) = v;
    }
  }
}

// ---------------- GRU recurrence, one chunk of CT steps ----------------
// h tile stored in A-fragment order: value h[r][k] at byte
//   (k>>5)*1024 + (((k>>3)&3)*16 + r)*16 + (k&7)*2
// so af read for (kk) = ds_read_b128 at lane*16 + kk*1024 (linear, conflict-free).
// Thread (w,l) produces h[g*4+q][w*32+jt*16+lr]: k>>5 == w for all its values,
// write byte = w*1024 + (lr>>3)*256 + g*64 + (lr&7)*2  + jt*512 + q*16.
__global__ __launch_bounds__(512, 2) void k_rec(
    const float* __restrict__ Whh_f, const float* __restrict__ bhh_f,
    const float* __restrict__ Whh_b, const float* __restrict__ bhh_b,
    const _Float16* __restrict__ gxc, float* __restrict__ wsh,
    _Float16* __restrict__ out16, float* __restrict__ hidden,
    int CT, int sbase)
{
  const int dir = blockIdx.x & 1;
  const int bsl = blockIdx.x >> 1;
  const int bbase = bsl * 16;
  const float* __restrict__ Whh = dir ? Whh_b : Whh_f;
  const float* __restrict__ bhh = dir ? bhh_b : bhh_f;
  const int tid = threadIdx.x, w = tid >> 6, l = tid & 63;
  const int lr = l & 15, g = l >> 4;
  const int j0 = w * 32;
  f16x8 wf[6][8];                            // B-frag: W[col][k=kk*32+g*8+i]
  #pragma unroll
  for (int ct = 0; ct < 6; ++ct) {
    const int colg = (ct>>1)*256 + j0 + (ct&1)*16 + lr;
    #pragma unroll
    for (int kk = 0; kk < 8; ++kk) {
      const float4* s4 = (const float4*)(Whh + (size_t)colg*256 + kk*32 + g*8);
      wf[ct][kk] = pack8(s4[0], s4[1]);
    }
  }
  const float bn0 = bhh[512 + j0 + lr];      // n-gate bhh (inside r*(.))
  const float bn1 = bhh[512 + j0 + 16 + lr];
  __shared__ _Float16 hs[2][4096];           // ping-pong A-frag-ordered h tiles (16KB)
  char* const afp = (char*)hs + l*16;                          // read base
  char* const hwp = (char*)hs + w*1024 + (lr>>3)*256 + g*64 + (lr&7)*2;  // write base
  float hold[2][4];
  if (sbase == 0) {
    *(int4*)((char*)hs + tid*16) = make_int4(0,0,0,0);         // hs[0] := 0 (8KB exact)
    #pragma unroll
    for (int jt = 0; jt < 2; ++jt)
      #pragma unroll
      for (int q = 0; q < 4; ++q) hold[jt][q] = 0.f;
  } else {                                   // restore h from previous chunk
    const int r = tid >> 5, kq = tid & 31;   // loads h[r][kq*8 .. +8]
    const float4* s4 = (const float4*)(wsh + ((size_t)(dir*64 + bbase + r))*256 + kq*8);
    *(f16x8*)((char*)hs + (kq>>2)*1024 + (((kq&3)*16) + r)*16) = pack8(s4[0], s4[1]);
    #pragma unroll
    for (int jt = 0; jt < 2; ++jt)
      #pragma unroll
      for (int q = 0; q < 4; ++q)
        hold[jt][q] = wsh[((size_t)(dir*64 + bbase + g*4 + q))*256 + j0 + jt*16 + lr];
  }
  __syncthreads();

  // hoisted moving pointers
  const int t0 = dir ? (1023 - sbase) : sbase;
  char* optr = (char*)out16 + ((size_t)t0*64 + bbase + g*4)*1024
             + (size_t)(dir*256 + j0 + lr)*2;
  const ptrdiff_t ostep = dir ? -(ptrdiff_t)65536 : (ptrdiff_t)65536;
  const _Float16* gp = gxc + (((size_t)dir*CT)*4 + bsl)*(size_t)(512*24) + (size_t)tid*24;
  const ptrdiff_t gstep = 4*512*24;
  f16x4 houts[2];                            // h(s-1) carried for deferred out-store
  bool sten = false;

#define REC_STEP(RB)                                                               \
  {                                                                                \
    const f16x8 gv0 = *(const f16x8*)(gp);                                         \
    const f16x8 gv1 = *(const f16x8*)(gp + 8);                                     \
    const f16x8 gv2 = *(const f16x8*)(gp + 16);                                    \
    gp += gstep;                                                                   \
    if (sten) {                              /* store h(s-1): full step to drain */\
      _Pragma("unroll")                                                            \
      for (int jt = 0; jt < 2; ++jt)                                               \
        _Pragma("unroll")                                                          \
        for (int q = 0; q < 4; ++q)                                                \
          *(_Float16*)(optr + q*1024 + jt*32) = houts[jt][q];                      \
      optr += ostep;                                                               \
    }                                                                              \
    sten = true;                                                                   \
    f32x4 acc[6];                                                                  \
    acc[0] = acc[1] = acc[2] = acc[3] = (f32x4){0.f,0.f,0.f,0.f};                  \
    acc[4] = (f32x4){bn0,bn0,bn0,bn0};                                             \
    acc[5] = (f32x4){bn1,bn1,bn1,bn1};                                             \
    _Pragma("unroll")                                                              \
    for (int kk = 0; kk < 8; ++kk) {                                               \
      f16x8 af = *(const f16x8*)(afp + (RB)*8192 + kk*1024);                       \
      _Pragma("unroll")                                                            \
      for (int ct = 0; ct < 6; ++ct) acc[ct] = MFMA(af, wf[ct][kk], acc[ct]);      \
    }                                                                              \
    _Pragma("unroll")                                                              \
    for (int jt = 0; jt < 2; ++jt) {                                               \
      _Pragma("unroll")                                                            \
      for (int q = 0; q < 4; ++q) {                                                \
        const float rg = fsigm((float)gv0[jt*4+q] + acc[jt][q]);                   \
        const float zg = fsigm((float)gv1[jt*4+q] + acc[2+jt][q]);                 \
        const float ng = ftanh((float)gv2[jt*4+q] + rg*acc[4+jt][q]);              \
        const float h = ng + zg*(hold[jt][q] - ng);                                \
        hold[jt][q] = h;                                                           \
        const _Float16 hf = (_Float16)h;                                           \
        houts[jt][q] = hf;                                                         \
        *(_Float16*)(hwp + ((RB)^1)*8192 + jt*512 + q*16) = hf;                    \
      }                                                                            \
    }                                                                              \
    __syncthreads();                                                               \
  }

  #pragma unroll 1
  for (int sc = 0; sc < CT; sc += 2) {
    REC_STEP(0)
    REC_STEP(1)
  }
#undef REC_STEP

  // store h(CT-1)
  #pragma unroll
  for (int jt = 0; jt < 2; ++jt)
    #pragma unroll
    for (int q = 0; q < 4; ++q)
      *(_Float16*)(optr + q*1024 + jt*32) = houts[jt][q];

  if (sbase + CT == 1024) {                  // final h -> hidden output
    #pragma unroll
    for (int jt = 0; jt < 2; ++jt)
      #pragma unroll
      for (int q = 0; q < 4; ++q)
        hidden[((size_t)(dir*64 + bbase + g*4 + q))*256 + j0 + jt*16 + lr] = hold[jt][q];
  } else {                                   // persist h for next chunk
    #pragma unroll
    for (int jt = 0; jt < 2; ++jt)
      #pragma unroll
      for (int q = 0; q < 4; ++q)
        wsh[((size_t)(dir*64 + bbase + g*4 + q))*256 + j0 + jt*16 + lr] = hold[jt][q];
  }
}

// ---------------- FC in place: relu(concat_f16 @ W_fc^T + b) -> f32 ----------------
__global__ __launch_bounds__(256) void k_fc(
    const _Float16* __restrict__ h16, const float* __restrict__ Wfc,
    const float* __restrict__ bfc, float* __restrict__ out)
{
  const int mt = blockIdx.x;
  __shared__ _Float16 As[64*512];            // 64KB
  const int tid = threadIdx.x, w = tid >> 6, l = tid & 63;
  const int lr = l & 15, g = l >> 4;
  #pragma unroll
  for (int i = 0; i < 16; ++i) {
    int c = tid + i*256, r = c >> 6, cc = c & 63;
    *(int4*)((char*)As + SWZ2(r, cc*16)) =
        *(const int4*)((const char*)h16 + ((size_t)mt*64 + r)*1024 + cc*16);
  }
  __syncthreads();                           // all h16 reads drained before any store
  #pragma unroll 1
  for (int nt = 0; nt < 4; ++nt) {
    f32x4 acc[4];
    #pragma unroll
    for (int ct = 0; ct < 4; ++ct) acc[ct] = (f32x4){0.f,0.f,0.f,0.f};
    #pragma unroll 2
    for (int kk = 0; kk < 16; ++kk) {
      f16x8 af = *(const f16x8*)((const char*)As + SWZ2(w*16 + lr, kk*64 + g*16));
      #pragma unroll
      for (int ct = 0; ct < 4; ++ct) {
        const float4* s4 = (const float4*)(Wfc + (size_t)(nt*64 + ct*16 + lr)*512 + kk*32 + g*8);
        acc[ct] = MFMA(af, pack8(s4[0], s4[1]), acc[ct]);
      }
    }
    #pragma unroll
    for (int ct = 0; ct < 4; ++ct) {
      const int col = nt*64 + ct*16 + lr;
      const float bv = bfc[col];
      #pragma unroll
      for (int q = 0; q < 4; ++q) {
        const int row = w*16 + g*4 + q;
        out[((size_t)mt*64 + row)*256 + col] = fmaxf(acc[ct][q] + bv, 0.f);
      }
    }
  }
}

extern "C" void kernel_launch(void* const* d_in, const int* in_sizes, int n_in,
                              void* d_out, int out_size, void* d_ws, size_t ws_size,
                              hipStream_t stream) {
  const float* X      = (const float*)d_in[0];
  const float* W_ih_f = (const float*)d_in[1];
  const float* W_hh_f = (const float*)d_in[2];
  const float* b_ih_f = (const float*)d_in[3];
  const float* b_hh_f = (const float*)d_in[4];
  const float* W_ih_b = (const float*)d_in[5];
  const float* W_hh_b = (const float*)d_in[6];
  const float* b_ih_b = (const float*)d_in[7];
  const float* b_hh_b = (const float*)d_in[8];
  const float* W_fc   = (const float*)d_in[9];
  const float* b_fc   = (const float*)d_in[10];

  // CT=256 keeps the gxc chunk (48MB) + X slice + out16 writes L3-resident.
  int CT = 256;
  while (CT > 8 && ((size_t)CT*196608 + 131072) > ws_size) CT >>= 1;
  _Float16* gxc = (_Float16*)d_ws;                     // [2][CT][4][512][24] f16
  float*    wsh = (float*)((char*)d_ws + (size_t)CT*196608);  // [2][64][256] f32

  _Float16* h16   = (_Float16*)d_out;                  // [1024][64][512] f16 (in-place)
  float*    out   = (float*)d_out;                     // [1024][64][256] f32
  float*    hidden= (float*)d_out + (size_t)1024*64*256;

  const int NC = 1024 / CT;
  for (int c = 0; c < NC; ++c) {
    k_gx<<<dim3(CT, 2), dim3(256), 0, stream>>>(X, W_ih_f, b_ih_f, b_hh_f,
                                                W_ih_b, b_ih_b, b_hh_b, gxc, CT, c*CT);
    k_rec<<<dim3(8), dim3(512), 0, stream>>>(W_hh_f, b_hh_f, W_hh_b, b_hh_b,
                                             gxc, wsh, h16, hidden, CT, c*CT);
  }
  k_fc<<<dim3(1024), dim3(256), 0, stream>>>(h16, W_fc, b_fc, out);
}